// Round 9
// baseline (271.679 us; speedup 1.0000x reference)
//
#include <hip/hip_runtime.h>
#include <math.h>

#define CC 256
#define HEADS 8
#define DD 32
#define GG 48
#define LL (GG*GG)      // 2304
#define NB 2
#define PTAB_N 95

typedef float f32x4 __attribute__((ext_vector_type(4)));
typedef _Float16 f16x8 __attribute__((ext_vector_type(8)));
typedef _Float16 f16x4 __attribute__((ext_vector_type(4)));

// workspace layout (floats).
// vbT/ebT alias xs (xs dead after gemm_qv+eb). po aliases qb (dead after attn).
#define OFF_XS   0
#define SZ_XS    (NB*CC*LL)           // 1,179,648
#define OFF_VBT  OFF_XS               // 786,432 floats (fp16 x 1,572,864)
#define OFF_EBT  (OFF_XS + 786432)    // 24,576 floats (fp16 x 49,152)
#define OFF_QB   (OFF_XS + SZ_XS)
#define SZ_QB    (NB*LL*CC)           // 1,179,648
#define OFF_PO   OFF_QB
#define OFF_VT   (OFF_QB + SZ_QB)
#define SZ_VT_F  (NB*CC*LL/2)         // vtb fp16, 589,824 floats
#define OFF_AO   (OFF_VT + SZ_VT_F)
#define SZ_AO    (NB*LL*CC)
#define OFF_EB   (OFF_AO + SZ_AO)
#define SZ_EB    (NB*HEADS*LL)
#define OFF_PTX  (OFF_EB + SZ_EB)
#define SZ_PT    (PTAB_N*CC)
#define OFF_PTY  (OFF_PTX + SZ_PT)
#define OFF_WB   (OFF_PTY + SZ_PT)

// ---------------- extract strided x ----------------
__global__ void k_extract(const float* __restrict__ x, float* __restrict__ xs) {
    int idx = blockIdx.x*256 + threadIdx.x;
    if (idx >= NB*CC*LL) return;
    int s = idx % LL; int c = (idx / LL) % CC; int n = idx / (CC*LL);
    int h = s / GG, w = s % GG;
    xs[idx] = x[((n*CC + c)*96 + 2*h)*96 + 2*w];
}

// ---------------- wb[i][c] = sum_d ab[i*32+d]*Wk[(i*32+d)][c] ----------------
__global__ void k_wb(const float* __restrict__ Wk, const float* __restrict__ ab,
                     float* __restrict__ wb) {
    int i = blockIdx.x; int c = threadIdx.x;
    float acc = 0.f;
    for (int d = 0; d < DD; ++d) acc += ab[i*DD+d] * Wk[(i*DD+d)*CC + c];
    wb[i*CC + c] = acc;
}

// ---------------- ptab[dd][o] = inv_s2 * sum_e emb(2*(dd-47))[e]*Wg[o][e] ----------------
__global__ void k_ptab(const float* __restrict__ Wgx, const float* __restrict__ Wgy,
                       float* __restrict__ ptx, float* __restrict__ pty) {
    __shared__ float emb[128];
    int ddv = blockIdx.x; int which = blockIdx.y;
    int t = threadIdx.x;
    float diff = 2.0f * (float)(ddv - 47);
    if (t < 64) {
        float dim = powf(1000.0f, (float)t / 64.0f);
        float ang = diff / dim;
        emb[t]      = sinf(ang);
        emb[t + 64] = cosf(ang);
    }
    __syncthreads();
    const float* Wg = which ? Wgy : Wgx;
    float* pt = which ? pty : ptx;
    float acc = 0.f;
    #pragma unroll 8
    for (int e = 0; e < 128; ++e) acc += emb[e] * Wg[t*128 + e];
    pt[ddv*CC + t] = acc * 0.70710678118654752f;
}

// ---------------- ebx[n][i][s] = exp(sum_c wb[i][c]*xs[n][c][s]) ----------------
__global__ void k_eb(const float* __restrict__ xs, const float* __restrict__ wb,
                     float* __restrict__ eb) {
    int s = blockIdx.x*256 + threadIdx.x;
    int n = blockIdx.y;
    float acc[HEADS] = {};
    const float* xp = xs + n*CC*LL + s;
    for (int c = 0; c < CC; ++c) {
        float xv = xp[c*LL];
        #pragma unroll
        for (int i = 0; i < HEADS; ++i) acc[i] += wb[i*CC+c] * xv;
    }
    #pragma unroll
    for (int i = 0; i < HEADS; ++i) eb[(n*HEADS+i)*LL + s] = __expf(acc[i]);
}

// ---------------- GEMM: [Wq;Wv](512x256) @ xs(256xL) ----------------
// Q rows -> qb fp32; V rows -> vtb fp16 (transposed: kv contiguous)
__global__ __launch_bounds__(256) void k_gemm_qv(const float* __restrict__ Wq,
                                                 const float* __restrict__ Wv,
                                                 const float* __restrict__ xs,
                                                 float* __restrict__ qb,
                                                 _Float16* __restrict__ vtb) {
    const int n  = blockIdx.z;
    const int m0 = blockIdx.y * 64;
    const int j0 = blockIdx.x * 64;
    __shared__ float As[16*68];
    __shared__ float Bs[16*68];
    const int t = threadIdx.x;
    const float* B = xs + n*CC*LL;
    float acc[4][4] = {};
    const int ty = t >> 4, tx = t & 15;
    for (int k0 = 0; k0 < CC; k0 += 16) {
        {
            int m = t >> 2, kq = t & 3;
            int o = m0 + m;
            const float* Arow = (o < CC) ? (Wq + o*CC) : (Wv + (o-CC)*CC);
            float4 av = *(const float4*)(Arow + k0 + kq*4);
            As[(kq*4+0)*68 + m] = av.x;
            As[(kq*4+1)*68 + m] = av.y;
            As[(kq*4+2)*68 + m] = av.z;
            As[(kq*4+3)*68 + m] = av.w;
            int kb = t >> 4, n4 = t & 15;
            float4 bv = *(const float4*)(B + (k0+kb)*LL + j0 + n4*4);
            *(float4*)(&Bs[kb*68 + n4*4]) = bv;
        }
        __syncthreads();
        #pragma unroll
        for (int k = 0; k < 16; ++k) {
            float4 a = *(const float4*)(&As[k*68 + ty*4]);
            float4 b = *(const float4*)(&Bs[k*68 + tx*4]);
            float av[4] = {a.x,a.y,a.z,a.w};
            float bv[4] = {b.x,b.y,b.z,b.w};
            #pragma unroll
            for (int p = 0; p < 4; ++p)
                #pragma unroll
                for (int q = 0; q < 4; ++q) acc[p][q] += av[p]*bv[q];
        }
        __syncthreads();
    }
    if (m0 < CC) {
        #pragma unroll
        for (int p = 0; p < 4; ++p) {
            int o = m0 + ty*4 + p;
            #pragma unroll
            for (int q = 0; q < 4; ++q)
                qb[(size_t)(n*LL + j0 + tx*4 + q)*CC + o] = acc[p][q];
        }
    } else {
        #pragma unroll
        for (int p = 0; p < 4; ++p) {
            int ch = m0 - CC + ty*4 + p;   // 0..255 == i*32+d
            f16x4 pk;
            pk[0] = (_Float16)acc[p][0];
            pk[1] = (_Float16)acc[p][1];
            pk[2] = (_Float16)acc[p][2];
            pk[3] = (_Float16)acc[p][3];
            *(f16x4*)(vtb + (size_t)(n*CC + ch)*LL + j0 + tx*4) = pk;
        }
    }
}

// ---------------- transpose V to u-contiguous, fold eb (no LDS) -------
// vbT[ni][v][d][64u] = ebx[ni][u*48+v] * V[ni][d][u*48+v]   (u>=48 zeroed)
// ebT[ni][v][64u]    = ebx[ni][u*48+v]                       (u>=48 zeroed)
__global__ void k_vtr(const _Float16* __restrict__ vtb, const float* __restrict__ ebx,
                      _Float16* __restrict__ vbT, _Float16* __restrict__ ebT) {
    const int ni = blockIdx.x;
    const int pair = blockIdx.y*256 + threadIdx.x;   // [0,1536)
    const int v = pair >> 5, d = pair & 31;
    const _Float16* vsrc = vtb + (size_t)(ni*32 + d)*LL;
    const float*  ebs  = ebx + (size_t)ni*LL;
    _Float16* dst = vbT + (size_t)ni*98304 + (size_t)(v*32 + d)*64;
    f16x8 z = {};
    #pragma unroll
    for (int c = 0; c < 6; ++c) {
        f16x8 o;
        #pragma unroll
        for (int e = 0; e < 8; ++e) {
            int u = c*8 + e;
            o[e] = (_Float16)((float)vsrc[u*48 + v] * ebs[u*48 + v]);
        }
        *(f16x8*)(dst + c*8) = o;
    }
    *(f16x8*)(dst + 48) = z;
    *(f16x8*)(dst + 56) = z;
    if (d == 0) {
        _Float16* ed = ebT + (size_t)ni*3072 + (size_t)v*64;
        #pragma unroll
        for (int c = 0; c < 6; ++c) {
            f16x8 o;
            #pragma unroll
            for (int e = 0; e < 8; ++e)
                o[e] = (_Float16)ebs[(c*8+e)*48 + v];
            *(f16x8*)(ed + c*8) = o;
        }
        *(f16x8*)(ed + 48) = z;
        *(f16x8*)(ed + 56) = z;
    }
}

// ---------------- attention v2: H = Ey' @ (eb.V), out = Ex-fold ----------------
// Ey' = exp(ey - rowmax) in fp16 (softmax ratio invariant to per-row scale).
__global__ __launch_bounds__(256) void k_attn(const float* __restrict__ qb,
                                              const _Float16* __restrict__ vbT,
                                              const _Float16* __restrict__ ebT,
                                              const float* __restrict__ ptx,
                                              const float* __restrict__ pty,
                                              float* __restrict__ ao) {
    const int t = threadIdx.x;
    const int lane = t & 63;
    const int mw = t >> 6;
    const int ni = blockIdx.y;
    const int n = ni >> 3, i = ni & 7;
    const int s0 = blockIdx.x * 64;

    __shared__ alignas(16) float    qs[64*32];
    __shared__ alignas(16) float    Eyr[64*49];   // raw ey
    __shared__ alignas(16) float    Exs[64*52];   // exp(Ex) f32
    __shared__ alignas(16) _Float16 Eys[64*72];   // exp(ey-max) fp16, u-pad to 64
    __shared__ float rowmax[64];

    // phase 0: stage Q tile
    #pragma unroll
    for (int l = 0; l < 2; ++l) {
        int f = t + 256*l;
        int r4 = f >> 3, dq = f & 7;
        float4 v4 = *(const float4*)(qb + (size_t)(n*LL + s0 + r4)*CC + i*32 + dq*4);
        *(float4*)(&qs[r4*32 + dq*4]) = v4;
    }
    __syncthreads();

    // phase 1a: raw ey -> Eyr; exp(ex) -> Exs
    for (int oidx = t; oidx < 64*96; oidx += 256) {
        int r = oidx / 96, j = oidx % 96;
        int s = s0 + r, h = s / GG, w = s % GG;
        int ddv; const float* tab;
        if (j < 48) { ddv = h - j + 47;      tab = pty; }
        else        { ddv = w - (j-48) + 47; tab = ptx; }
        const float4* tp = (const float4*)(tab + ddv*CC + i*32);
        const float4* qp = (const float4*)(qs + r*32);
        float acc = 0.f;
        #pragma unroll
        for (int d4 = 0; d4 < 8; ++d4) {
            float4 a = qp[d4]; float4 b = tp[d4];
            acc += a.x*b.x + a.y*b.y + a.z*b.z + a.w*b.w;
        }
        if (j < 48) Eyr[r*49 + j] = acc;
        else        Exs[r*52 + (j-48)] = __expf(acc);
    }
    __syncthreads();
    // phase 1b: per-row max of ey
    if (t < 64) {
        float m = -1e30f;
        #pragma unroll 8
        for (int j = 0; j < 48; ++j) m = fmaxf(m, Eyr[t*49 + j]);
        rowmax[t] = m;
    }
    __syncthreads();
    // phase 1c: normalized fp16 Ey + zero-pad u 48..63
    for (int idx = t; idx < 64*48; idx += 256) {
        int r = idx / 48, j = idx % 48;
        Eys[r*72 + j] = (_Float16)__expf(Eyr[r*49 + j] - rowmax[r]);
    }
    for (int zi = t; zi < 64*16; zi += 256) {
        int r = zi >> 4, c = zi & 15;
        Eys[r*72 + 48 + c] = (_Float16)0.f;
    }
    __syncthreads();

    const int r = lane & 15, g = lane >> 4;
    const int rowA = mw*16 + r;          // A-frag s-row
    const int rowD = mw*16 + g*4;        // D rows rowD..rowD+3

    f16x8 a0 = *(const f16x8*)(Eys + rowA*72 + g*8);
    f16x8 a1 = *(const f16x8*)(Eys + rowA*72 + 32 + g*8);

    const _Float16* vb = vbT + (size_t)ni*(48*32*64);
    const _Float16* et = ebT + (size_t)ni*(48*64);

    // HS = Ey' @ ebT  (3 n-frags of 16 v)
    f32x4 hs0, hs1, hs2;
    {
        f32x4 zv = {0.f,0.f,0.f,0.f};
        f16x8 b0 = *(const f16x8*)(et + (0*16 + r)*64 + g*8);
        f16x8 b1 = *(const f16x8*)(et + (0*16 + r)*64 + 32 + g*8);
        hs0 = __builtin_amdgcn_mfma_f32_16x16x32_f16(a0, b0, zv, 0,0,0);
        hs0 = __builtin_amdgcn_mfma_f32_16x16x32_f16(a1, b1, hs0, 0,0,0);
        b0 = *(const f16x8*)(et + (1*16 + r)*64 + g*8);
        b1 = *(const f16x8*)(et + (1*16 + r)*64 + 32 + g*8);
        hs1 = __builtin_amdgcn_mfma_f32_16x16x32_f16(a0, b0, zv, 0,0,0);
        hs1 = __builtin_amdgcn_mfma_f32_16x16x32_f16(a1, b1, hs1, 0,0,0);
        b0 = *(const f16x8*)(et + (2*16 + r)*64 + g*8);
        b1 = *(const f16x8*)(et + (2*16 + r)*64 + 32 + g*8);
        hs2 = __builtin_amdgcn_mfma_f32_16x16x32_f16(a0, b0, zv, 0,0,0);
        hs2 = __builtin_amdgcn_mfma_f32_16x16x32_f16(a1, b1, hs2, 0,0,0);
    }
    // S[s] = sum_v Ex * HS ; butterfly over 16 v-cols
    float Sp[4];
    #pragma unroll
    for (int reg = 0; reg < 4; ++reg) {
        Sp[reg] = Exs[(rowD+reg)*52 +  0 + r] * hs0[reg]
                + Exs[(rowD+reg)*52 + 16 + r] * hs1[reg]
                + Exs[(rowD+reg)*52 + 32 + r] * hs2[reg];
    }
    #pragma unroll
    for (int m = 1; m <= 8; m <<= 1) {
        #pragma unroll
        for (int reg = 0; reg < 4; ++reg)
            Sp[reg] += __shfl_xor(Sp[reg], m, 64);
    }

    // main loop: 12 v-groups of 4; H-frags folded immediately via Ex
    f32x4 oacc0 = {0.f,0.f,0.f,0.f}, oacc1 = {0.f,0.f,0.f,0.f};
    for (int v0 = 0; v0 < 48; v0 += 4) {
        float4 ex0 = *(const float4*)(Exs + (rowD+0)*52 + v0);
        float4 ex1 = *(const float4*)(Exs + (rowD+1)*52 + v0);
        float4 ex2 = *(const float4*)(Exs + (rowD+2)*52 + v0);
        float4 ex3 = *(const float4*)(Exs + (rowD+3)*52 + v0);
        #pragma unroll
        for (int vl = 0; vl < 4; ++vl) {
            const float e0 = (vl==0)?ex0.x:(vl==1)?ex0.y:(vl==2)?ex0.z:ex0.w;
            const float e1 = (vl==0)?ex1.x:(vl==1)?ex1.y:(vl==2)?ex1.z:ex1.w;
            const float e2 = (vl==0)?ex2.x:(vl==1)?ex2.y:(vl==2)?ex2.z:ex2.w;
            const float e3 = (vl==0)?ex3.x:(vl==1)?ex3.y:(vl==2)?ex3.z:ex3.w;
            #pragma unroll
            for (int dh = 0; dh < 2; ++dh) {
                const _Float16* bp = vb + ((size_t)((v0+vl)*32 + dh*16 + r)*64) + g*8;
                f16x8 b0 = *(const f16x8*)(bp);
                f16x8 b1 = *(const f16x8*)(bp + 32);
                f32x4 hz = {0.f,0.f,0.f,0.f};
                hz = __builtin_amdgcn_mfma_f32_16x16x32_f16(a0, b0, hz, 0,0,0);
                hz = __builtin_amdgcn_mfma_f32_16x16x32_f16(a1, b1, hz, 0,0,0);
                if (dh == 0) {
                    oacc0[0] += e0*hz[0]; oacc0[1] += e1*hz[1];
                    oacc0[2] += e2*hz[2]; oacc0[3] += e3*hz[3];
                } else {
                    oacc1[0] += e0*hz[0]; oacc1[1] += e1*hz[1];
                    oacc1[2] += e2*hz[2]; oacc1[3] += e3*hz[3];
                }
            }
        }
    }

    // write normalized output (Sp>0 always when healthy; fmaxf = NaN guard)
    #pragma unroll
    for (int reg = 0; reg < 4; ++reg) {
        float inv = 1.0f / fmaxf(Sp[reg], 1e-30f);
        size_t base = (size_t)(n*LL + s0 + rowD + reg)*CC + i*32;
        ao[base + r]      = oacc0[reg] * inv;
        ao[base + 16 + r] = oacc1[reg] * inv;
    }
}

// ---------------- proj GEMM: Wproj(256x256) @ ao^T -> po[n][o][s] ----------------
__global__ __launch_bounds__(256) void k_gemm_proj(const float* __restrict__ Wp,
                                                   const float* __restrict__ ao,
                                                   float* __restrict__ po) {
    const int n  = blockIdx.z;
    const int m0 = blockIdx.y * 64;
    const int j0 = blockIdx.x * 64;
    __shared__ float As[16*68];
    __shared__ float Bs[16*68];
    const int t = threadIdx.x;
    const float* Bt = ao + (size_t)n*LL*CC;   // [j][k]
    float acc[4][4] = {};
    const int ty = t >> 4, tx = t & 15;
    for (int k0 = 0; k0 < CC; k0 += 16) {
        {
            int m = t >> 2, kq = t & 3;
            float4 av = *(const float4*)(Wp + (m0+m)*CC + k0 + kq*4);
            As[(kq*4+0)*68 + m] = av.x;
            As[(kq*4+1)*68 + m] = av.y;
            As[(kq*4+2)*68 + m] = av.z;
            As[(kq*4+3)*68 + m] = av.w;
            float4 bv = *(const float4*)(Bt + (size_t)(j0+m)*CC + k0 + kq*4);
            Bs[(kq*4+0)*68 + m] = bv.x;
            Bs[(kq*4+1)*68 + m] = bv.y;
            Bs[(kq*4+2)*68 + m] = bv.z;
            Bs[(kq*4+3)*68 + m] = bv.w;
        }
        __syncthreads();
        #pragma unroll
        for (int k = 0; k < 16; ++k) {
            float4 a = *(const float4*)(&As[k*68 + ty*4]);
            float4 b = *(const float4*)(&Bs[k*68 + tx*4]);
            float av[4] = {a.x,a.y,a.z,a.w};
            float bv[4] = {b.x,b.y,b.z,b.w};
            #pragma unroll
            for (int p = 0; p < 4; ++p)
                #pragma unroll
                for (int q = 0; q < 4; ++q) acc[p][q] += av[p]*bv[q];
        }
        __syncthreads();
    }
    #pragma unroll
    for (int p = 0; p < 4; ++p) {
        int o = m0 + ty*4 + p;
        float4 ov = make_float4(acc[p][0],acc[p][1],acc[p][2],acc[p][3]);
        *(float4*)(po + (size_t)n*CC*LL + (size_t)o*LL + j0 + tx*4) = ov;
    }
}

// ---------------- bilinear x2 upsample + bias + gamma + residual ----------------
__global__ void k_final(const float* __restrict__ x, const float* __restrict__ po,
                        const float* __restrict__ bproj, const float* __restrict__ gammap,
                        float* __restrict__ out) {
    int idx = blockIdx.x*256 + threadIdx.x;
    if (idx >= NB*CC*96*96) return;
    int X = idx % 96, Y = (idx/96) % 96, o = (idx/(96*96)) % CC, n = idx/(96*96*CC);
    float gamma = gammap[0];
    float yf = Y*0.5f - 0.25f, xf = X*0.5f - 0.25f;
    float y0f = floorf(yf), x0f = floorf(xf);
    float tyy = yf - y0f, txx = xf - x0f;
    int y0 = (int)y0f, x0 = (int)x0f;
    int iy0 = max(y0,0), iy1 = min(y0+1,GG-1);
    int ix0 = max(x0,0), ix1 = min(x0+1,GG-1);
    const float* pp = po + (size_t)(n*CC + o)*LL;
    float v00 = pp[iy0*GG+ix0], v01 = pp[iy0*GG+ix1];
    float v10 = pp[iy1*GG+ix0], v11 = pp[iy1*GG+ix1];
    float vy0 = v00 + txx*(v01-v00);
    float vy1 = v10 + txx*(v11-v10);
    float bil = vy0 + tyy*(vy1-vy0);
    out[idx] = gamma*(bil + bproj[o]) + x[idx];
}

extern "C" void kernel_launch(void* const* d_in, const int* in_sizes, int n_in,
                              void* d_out, int out_size, void* d_ws, size_t ws_size,
                              hipStream_t stream) {
    const float* x   = (const float*)d_in[0];
    const float* Wq  = (const float*)d_in[1];
    const float* Wk  = (const float*)d_in[2];
    const float* Wv  = (const float*)d_in[3];
    const float* Wgx = (const float*)d_in[4];
    const float* Wgy = (const float*)d_in[5];
    const float* ab  = (const float*)d_in[6];
    const float* Wp  = (const float*)d_in[7];
    const float* bp  = (const float*)d_in[8];
    const float* gm  = (const float*)d_in[9];
    float* ws = (float*)d_ws;
    float* xs  = ws + OFF_XS;
    _Float16* vbT = (_Float16*)(ws + OFF_VBT);
    _Float16* ebT = (_Float16*)(ws + OFF_EBT);
    float* qbp = ws + OFF_QB;
    _Float16* vtb = (_Float16*)(ws + OFF_VT);
    float* aop = ws + OFF_AO;
    float* ebp = ws + OFF_EB;
    float* ptxp= ws + OFF_PTX;
    float* ptyp= ws + OFF_PTY;
    float* wbp = ws + OFF_WB;
    float* pop = ws + OFF_PO;      // aliases qb
    float* out = (float*)d_out;

    k_extract<<<(NB*CC*LL + 255)/256, 256, 0, stream>>>(x, xs);
    k_wb<<<HEADS, 256, 0, stream>>>(Wk, ab, wbp);
    k_ptab<<<dim3(PTAB_N, 2), 256, 0, stream>>>(Wgx, Wgy, ptxp, ptyp);
    k_eb<<<dim3(LL/256, NB), 256, 0, stream>>>(xs, wbp, ebp);
    k_gemm_qv<<<dim3(LL/64, 8, NB), 256, 0, stream>>>(Wq, Wv, xs, qbp, vtb);
    k_vtr<<<dim3(NB*HEADS, 6), 256, 0, stream>>>(vtb, ebp, vbT, ebT);
    k_attn<<<dim3(LL/64, NB*HEADS), 256, 0, stream>>>(qbp, vbT, ebT, ptxp, ptyp, aop);
    k_gemm_proj<<<dim3(LL/64, 4, NB), 256, 0, stream>>>(Wp, aop, pop);
    k_final<<<(NB*CC*96*96 + 255)/256, 256, 0, stream>>>(x, pop, bp, gm, out);
}

// Round 10
// 240.869 us; speedup vs baseline: 1.1279x; 1.1279x over previous
//
#include <hip/hip_runtime.h>
#include <math.h>

#define CC 256
#define HEADS 8
#define DD 32
#define GG 48
#define LL (GG*GG)      // 2304
#define NB 2
#define PTAB_N 95

typedef float f32x4 __attribute__((ext_vector_type(4)));
typedef _Float16 f16x8 __attribute__((ext_vector_type(8)));
typedef _Float16 f16x4 __attribute__((ext_vector_type(4)));

// workspace layout (floats).
// vbT/ebT alias xs (xs dead after gemm_qv+eb). po aliases qb (dead after attn).
#define OFF_XS   0
#define SZ_XS    (NB*CC*LL)           // 1,179,648
#define OFF_VBT  OFF_XS               // 786,432 floats (fp16 x 1,572,864)
#define OFF_EBT  (OFF_XS + 786432)    // 24,576 floats (fp16 x 49,152)
#define OFF_QB   (OFF_XS + SZ_XS)
#define SZ_QB    (NB*LL*CC)           // 1,179,648
#define OFF_PO   OFF_QB
#define OFF_VT   (OFF_QB + SZ_QB)
#define SZ_VT_F  (NB*CC*LL/2)         // vtb fp16, 589,824 floats
#define OFF_AO   (OFF_VT + SZ_VT_F)
#define SZ_AO    (NB*LL*CC)
#define OFF_EB   (OFF_AO + SZ_AO)
#define SZ_EB    (NB*HEADS*LL)
#define OFF_PTX  (OFF_EB + SZ_EB)
#define SZ_PT    (PTAB_N*CC)
#define OFF_PTY  (OFF_PTX + SZ_PT)
#define OFF_WB   (OFF_PTY + SZ_PT)

// ---------------- extract strided x ----------------
__global__ void k_extract(const float* __restrict__ x, float* __restrict__ xs) {
    int idx = blockIdx.x*256 + threadIdx.x;
    if (idx >= NB*CC*LL) return;
    int s = idx % LL; int c = (idx / LL) % CC; int n = idx / (CC*LL);
    int h = s / GG, w = s % GG;
    xs[idx] = x[((n*CC + c)*96 + 2*h)*96 + 2*w];
}

// ---------------- wb[i][c] = sum_d ab[i*32+d]*Wk[(i*32+d)][c] ----------------
__global__ void k_wb(const float* __restrict__ Wk, const float* __restrict__ ab,
                     float* __restrict__ wb) {
    int i = blockIdx.x; int c = threadIdx.x;
    float acc = 0.f;
    for (int d = 0; d < DD; ++d) acc += ab[i*DD+d] * Wk[(i*DD+d)*CC + c];
    wb[i*CC + c] = acc;
}

// ---------------- ptab[dd][o] = inv_s2 * sum_e emb(2*(dd-47))[e]*Wg[o][e] ----------------
__global__ void k_ptab(const float* __restrict__ Wgx, const float* __restrict__ Wgy,
                       float* __restrict__ ptx, float* __restrict__ pty) {
    __shared__ float emb[128];
    int ddv = blockIdx.x; int which = blockIdx.y;
    int t = threadIdx.x;
    float diff = 2.0f * (float)(ddv - 47);
    if (t < 64) {
        float dim = powf(1000.0f, (float)t / 64.0f);
        float ang = diff / dim;
        emb[t]      = sinf(ang);
        emb[t + 64] = cosf(ang);
    }
    __syncthreads();
    const float* Wg = which ? Wgy : Wgx;
    float* pt = which ? pty : ptx;
    float acc = 0.f;
    #pragma unroll 8
    for (int e = 0; e < 128; ++e) acc += emb[e] * Wg[t*128 + e];
    pt[ddv*CC + t] = acc * 0.70710678118654752f;
}

// ---------------- ebx[n][i][s] = exp(sum_c wb[i][c]*xs[n][c][s]) ----------------
__global__ void k_eb(const float* __restrict__ xs, const float* __restrict__ wb,
                     float* __restrict__ eb) {
    int s = blockIdx.x*256 + threadIdx.x;
    int n = blockIdx.y;
    float acc[HEADS] = {};
    const float* xp = xs + n*CC*LL + s;
    for (int c = 0; c < CC; ++c) {
        float xv = xp[c*LL];
        #pragma unroll
        for (int i = 0; i < HEADS; ++i) acc[i] += wb[i*CC+c] * xv;
    }
    #pragma unroll
    for (int i = 0; i < HEADS; ++i) eb[(n*HEADS+i)*LL + s] = __expf(acc[i]);
}

// ---------------- GEMM: [Wq;Wv](512x256) @ xs(256xL) ----------------
// Q rows -> qb fp32; V rows -> vtb fp16 (transposed: kv contiguous)
__global__ __launch_bounds__(256) void k_gemm_qv(const float* __restrict__ Wq,
                                                 const float* __restrict__ Wv,
                                                 const float* __restrict__ xs,
                                                 float* __restrict__ qb,
                                                 _Float16* __restrict__ vtb) {
    const int n  = blockIdx.z;
    const int m0 = blockIdx.y * 64;
    const int j0 = blockIdx.x * 64;
    __shared__ float As[16*68];
    __shared__ float Bs[16*68];
    const int t = threadIdx.x;
    const float* B = xs + n*CC*LL;
    float acc[4][4] = {};
    const int ty = t >> 4, tx = t & 15;
    for (int k0 = 0; k0 < CC; k0 += 16) {
        {
            int m = t >> 2, kq = t & 3;
            int o = m0 + m;
            const float* Arow = (o < CC) ? (Wq + o*CC) : (Wv + (o-CC)*CC);
            float4 av = *(const float4*)(Arow + k0 + kq*4);
            As[(kq*4+0)*68 + m] = av.x;
            As[(kq*4+1)*68 + m] = av.y;
            As[(kq*4+2)*68 + m] = av.z;
            As[(kq*4+3)*68 + m] = av.w;
            int kb = t >> 4, n4 = t & 15;
            float4 bv = *(const float4*)(B + (k0+kb)*LL + j0 + n4*4);
            *(float4*)(&Bs[kb*68 + n4*4]) = bv;
        }
        __syncthreads();
        #pragma unroll
        for (int k = 0; k < 16; ++k) {
            float4 a = *(const float4*)(&As[k*68 + ty*4]);
            float4 b = *(const float4*)(&Bs[k*68 + tx*4]);
            float av[4] = {a.x,a.y,a.z,a.w};
            float bv[4] = {b.x,b.y,b.z,b.w};
            #pragma unroll
            for (int p = 0; p < 4; ++p)
                #pragma unroll
                for (int q = 0; q < 4; ++q) acc[p][q] += av[p]*bv[q];
        }
        __syncthreads();
    }
    if (m0 < CC) {
        #pragma unroll
        for (int p = 0; p < 4; ++p) {
            int o = m0 + ty*4 + p;
            #pragma unroll
            for (int q = 0; q < 4; ++q)
                qb[(size_t)(n*LL + j0 + tx*4 + q)*CC + o] = acc[p][q];
        }
    } else {
        #pragma unroll
        for (int p = 0; p < 4; ++p) {
            int ch = m0 - CC + ty*4 + p;   // 0..255 == i*32+d
            f16x4 pk;
            pk[0] = (_Float16)acc[p][0];
            pk[1] = (_Float16)acc[p][1];
            pk[2] = (_Float16)acc[p][2];
            pk[3] = (_Float16)acc[p][3];
            *(f16x4*)(vtb + (size_t)(n*CC + ch)*LL + j0 + tx*4) = pk;
        }
    }
}

// ---------------- transpose V to u-contiguous, fold eb (no LDS) -------
// vbT[ni][v][d][64u] = ebx[ni][u*48+v] * V[ni][d][u*48+v]   (u>=48 zeroed)
// ebT[ni][v][64u]    = ebx[ni][u*48+v]                       (u>=48 zeroed)
__global__ void k_vtr(const _Float16* __restrict__ vtb, const float* __restrict__ ebx,
                      _Float16* __restrict__ vbT, _Float16* __restrict__ ebT) {
    const int ni = blockIdx.x;
    const int pair = blockIdx.y*256 + threadIdx.x;   // [0,1536)
    const int v = pair >> 5, d = pair & 31;
    const _Float16* vsrc = vtb + (size_t)(ni*32 + d)*LL;
    const float*  ebs  = ebx + (size_t)ni*LL;
    _Float16* dst = vbT + (size_t)ni*98304 + (size_t)(v*32 + d)*64;
    f16x8 z = {};
    #pragma unroll
    for (int c = 0; c < 6; ++c) {
        f16x8 o;
        #pragma unroll
        for (int e = 0; e < 8; ++e) {
            int u = c*8 + e;
            o[e] = (_Float16)((float)vsrc[u*48 + v] * ebs[u*48 + v]);
        }
        *(f16x8*)(dst + c*8) = o;
    }
    *(f16x8*)(dst + 48) = z;
    *(f16x8*)(dst + 56) = z;
    if (d == 0) {
        _Float16* ed = ebT + (size_t)ni*3072 + (size_t)v*64;
        #pragma unroll
        for (int c = 0; c < 6; ++c) {
            f16x8 o;
            #pragma unroll
            for (int e = 0; e < 8; ++e)
                o[e] = (_Float16)ebs[(c*8+e)*48 + v];
            *(f16x8*)(ed + c*8) = o;
        }
        *(f16x8*)(ed + 48) = z;
        *(f16x8*)(ed + 56) = z;
    }
}

// ---------------- attention v2: H = Ey' @ (eb.V), out = Ex-fold ----------------
// Ey' = exp(ey - rowmax) in fp16 (softmax ratio invariant to per-row scale).
// #pragma unroll 1 on the main loop: full unroll blew VGPR to 256 + spills (r9).
__global__ __launch_bounds__(256) void k_attn(const float* __restrict__ qb,
                                              const _Float16* __restrict__ vbT,
                                              const _Float16* __restrict__ ebT,
                                              const float* __restrict__ ptx,
                                              const float* __restrict__ pty,
                                              float* __restrict__ ao) {
    const int t = threadIdx.x;
    const int lane = t & 63;
    const int mw = t >> 6;
    const int ni = blockIdx.y;
    const int n = ni >> 3, i = ni & 7;
    const int s0 = blockIdx.x * 64;

    __shared__ alignas(16) float    qs[64*32];
    __shared__ alignas(16) float    Eyr[64*49];   // raw ey
    __shared__ alignas(16) float    Exs[64*52];   // exp(Ex) f32
    __shared__ alignas(16) _Float16 Eys[64*72];   // exp(ey-max) fp16, u-pad to 64
    __shared__ float rowmax[64];

    // phase 0: stage Q tile
    #pragma unroll
    for (int l = 0; l < 2; ++l) {
        int f = t + 256*l;
        int r4 = f >> 3, dq = f & 7;
        float4 v4 = *(const float4*)(qb + (size_t)(n*LL + s0 + r4)*CC + i*32 + dq*4);
        *(float4*)(&qs[r4*32 + dq*4]) = v4;
    }
    __syncthreads();

    // phase 1a: raw ey -> Eyr; exp(ex) -> Exs
    for (int oidx = t; oidx < 64*96; oidx += 256) {
        int r = oidx / 96, j = oidx % 96;
        int s = s0 + r, h = s / GG, w = s % GG;
        int ddv; const float* tab;
        if (j < 48) { ddv = h - j + 47;      tab = pty; }
        else        { ddv = w - (j-48) + 47; tab = ptx; }
        const float4* tp = (const float4*)(tab + ddv*CC + i*32);
        const float4* qp = (const float4*)(qs + r*32);
        float acc = 0.f;
        #pragma unroll
        for (int d4 = 0; d4 < 8; ++d4) {
            float4 a = qp[d4]; float4 b = tp[d4];
            acc += a.x*b.x + a.y*b.y + a.z*b.z + a.w*b.w;
        }
        if (j < 48) Eyr[r*49 + j] = acc;
        else        Exs[r*52 + (j-48)] = __expf(acc);
    }
    __syncthreads();
    // phase 1b: per-row max of ey
    if (t < 64) {
        float m = -1e30f;
        #pragma unroll 8
        for (int j = 0; j < 48; ++j) m = fmaxf(m, Eyr[t*49 + j]);
        rowmax[t] = m;
    }
    __syncthreads();
    // phase 1c: normalized fp16 Ey + zero-pad u 48..63
    for (int idx = t; idx < 64*48; idx += 256) {
        int r = idx / 48, j = idx % 48;
        Eys[r*72 + j] = (_Float16)__expf(Eyr[r*49 + j] - rowmax[r]);
    }
    for (int zi = t; zi < 64*16; zi += 256) {
        int r = zi >> 4, c = zi & 15;
        Eys[r*72 + 48 + c] = (_Float16)0.f;
    }
    __syncthreads();

    const int r = lane & 15, g = lane >> 4;
    const int rowA = mw*16 + r;          // A-frag s-row
    const int rowD = mw*16 + g*4;        // D rows rowD..rowD+3

    f16x8 a0 = *(const f16x8*)(Eys + rowA*72 + g*8);
    f16x8 a1 = *(const f16x8*)(Eys + rowA*72 + 32 + g*8);

    const _Float16* vb = vbT + (size_t)ni*(48*32*64);
    const _Float16* et = ebT + (size_t)ni*(48*64);

    // HS = Ey' @ ebT  (3 n-frags of 16 v)
    f32x4 hs0, hs1, hs2;
    {
        f32x4 zv = {0.f,0.f,0.f,0.f};
        f16x8 b0 = *(const f16x8*)(et + (0*16 + r)*64 + g*8);
        f16x8 b1 = *(const f16x8*)(et + (0*16 + r)*64 + 32 + g*8);
        hs0 = __builtin_amdgcn_mfma_f32_16x16x32_f16(a0, b0, zv, 0,0,0);
        hs0 = __builtin_amdgcn_mfma_f32_16x16x32_f16(a1, b1, hs0, 0,0,0);
        b0 = *(const f16x8*)(et + (1*16 + r)*64 + g*8);
        b1 = *(const f16x8*)(et + (1*16 + r)*64 + 32 + g*8);
        hs1 = __builtin_amdgcn_mfma_f32_16x16x32_f16(a0, b0, zv, 0,0,0);
        hs1 = __builtin_amdgcn_mfma_f32_16x16x32_f16(a1, b1, hs1, 0,0,0);
        b0 = *(const f16x8*)(et + (2*16 + r)*64 + g*8);
        b1 = *(const f16x8*)(et + (2*16 + r)*64 + 32 + g*8);
        hs2 = __builtin_amdgcn_mfma_f32_16x16x32_f16(a0, b0, zv, 0,0,0);
        hs2 = __builtin_amdgcn_mfma_f32_16x16x32_f16(a1, b1, hs2, 0,0,0);
    }
    // S[s] = sum_v Ex * HS ; butterfly over 16 v-cols
    float Sp[4];
    #pragma unroll
    for (int reg = 0; reg < 4; ++reg) {
        Sp[reg] = Exs[(rowD+reg)*52 +  0 + r] * hs0[reg]
                + Exs[(rowD+reg)*52 + 16 + r] * hs1[reg]
                + Exs[(rowD+reg)*52 + 32 + r] * hs2[reg];
    }
    #pragma unroll
    for (int m = 1; m <= 8; m <<= 1) {
        #pragma unroll
        for (int reg = 0; reg < 4; ++reg)
            Sp[reg] += __shfl_xor(Sp[reg], m, 64);
    }

    // main loop: 12 v-groups of 4; H-frags folded immediately via Ex.
    // unroll 1: prevent full unroll -> VGPR blowup -> scratch spill (r9 lesson)
    f32x4 oacc0 = {0.f,0.f,0.f,0.f}, oacc1 = {0.f,0.f,0.f,0.f};
    #pragma unroll 1
    for (int v0 = 0; v0 < 48; v0 += 4) {
        float4 ex0 = *(const float4*)(Exs + (rowD+0)*52 + v0);
        float4 ex1 = *(const float4*)(Exs + (rowD+1)*52 + v0);
        float4 ex2 = *(const float4*)(Exs + (rowD+2)*52 + v0);
        float4 ex3 = *(const float4*)(Exs + (rowD+3)*52 + v0);
        #pragma unroll 2
        for (int vl = 0; vl < 4; ++vl) {
            const float e0 = (vl==0)?ex0.x:(vl==1)?ex0.y:(vl==2)?ex0.z:ex0.w;
            const float e1 = (vl==0)?ex1.x:(vl==1)?ex1.y:(vl==2)?ex1.z:ex1.w;
            const float e2 = (vl==0)?ex2.x:(vl==1)?ex2.y:(vl==2)?ex2.z:ex2.w;
            const float e3 = (vl==0)?ex3.x:(vl==1)?ex3.y:(vl==2)?ex3.z:ex3.w;
            #pragma unroll
            for (int dh = 0; dh < 2; ++dh) {
                const _Float16* bp = vb + ((size_t)((v0+vl)*32 + dh*16 + r)*64) + g*8;
                f16x8 b0 = *(const f16x8*)(bp);
                f16x8 b1 = *(const f16x8*)(bp + 32);
                f32x4 hz = {0.f,0.f,0.f,0.f};
                hz = __builtin_amdgcn_mfma_f32_16x16x32_f16(a0, b0, hz, 0,0,0);
                hz = __builtin_amdgcn_mfma_f32_16x16x32_f16(a1, b1, hz, 0,0,0);
                if (dh == 0) {
                    oacc0[0] += e0*hz[0]; oacc0[1] += e1*hz[1];
                    oacc0[2] += e2*hz[2]; oacc0[3] += e3*hz[3];
                } else {
                    oacc1[0] += e0*hz[0]; oacc1[1] += e1*hz[1];
                    oacc1[2] += e2*hz[2]; oacc1[3] += e3*hz[3];
                }
            }
        }
    }

    // write normalized output (Sp>0 always when healthy; fmaxf = NaN guard)
    #pragma unroll
    for (int reg = 0; reg < 4; ++reg) {
        float inv = 1.0f / fmaxf(Sp[reg], 1e-30f);
        size_t base = (size_t)(n*LL + s0 + rowD + reg)*CC + i*32;
        ao[base + r]      = oacc0[reg] * inv;
        ao[base + 16 + r] = oacc1[reg] * inv;
    }
}

// ---------------- proj GEMM: Wproj(256x256) @ ao^T -> po[n][o][s] ----------------
__global__ __launch_bounds__(256) void k_gemm_proj(const float* __restrict__ Wp,
                                                   const float* __restrict__ ao,
                                                   float* __restrict__ po) {
    const int n  = blockIdx.z;
    const int m0 = blockIdx.y * 64;
    const int j0 = blockIdx.x * 64;
    __shared__ float As[16*68];
    __shared__ float Bs[16*68];
    const int t = threadIdx.x;
    const float* Bt = ao + (size_t)n*LL*CC;   // [j][k]
    float acc[4][4] = {};
    const int ty = t >> 4, tx = t & 15;
    for (int k0 = 0; k0 < CC; k0 += 16) {
        {
            int m = t >> 2, kq = t & 3;
            float4 av = *(const float4*)(Wp + (m0+m)*CC + k0 + kq*4);
            As[(kq*4+0)*68 + m] = av.x;
            As[(kq*4+1)*68 + m] = av.y;
            As[(kq*4+2)*68 + m] = av.z;
            As[(kq*4+3)*68 + m] = av.w;
            float4 bv = *(const float4*)(Bt + (size_t)(j0+m)*CC + k0 + kq*4);
            Bs[(kq*4+0)*68 + m] = bv.x;
            Bs[(kq*4+1)*68 + m] = bv.y;
            Bs[(kq*4+2)*68 + m] = bv.z;
            Bs[(kq*4+3)*68 + m] = bv.w;
        }
        __syncthreads();
        #pragma unroll
        for (int k = 0; k < 16; ++k) {
            float4 a = *(const float4*)(&As[k*68 + ty*4]);
            float4 b = *(const float4*)(&Bs[k*68 + tx*4]);
            float av[4] = {a.x,a.y,a.z,a.w};
            float bv[4] = {b.x,b.y,b.z,b.w};
            #pragma unroll
            for (int p = 0; p < 4; ++p)
                #pragma unroll
                for (int q = 0; q < 4; ++q) acc[p][q] += av[p]*bv[q];
        }
        __syncthreads();
    }
    #pragma unroll
    for (int p = 0; p < 4; ++p) {
        int o = m0 + ty*4 + p;
        float4 ov = make_float4(acc[p][0],acc[p][1],acc[p][2],acc[p][3]);
        *(float4*)(po + (size_t)n*CC*LL + (size_t)o*LL + j0 + tx*4) = ov;
    }
}

// ---------------- bilinear x2 upsample + bias + gamma + residual ----------------
__global__ void k_final(const float* __restrict__ x, const float* __restrict__ po,
                        const float* __restrict__ bproj, const float* __restrict__ gammap,
                        float* __restrict__ out) {
    int idx = blockIdx.x*256 + threadIdx.x;
    if (idx >= NB*CC*96*96) return;
    int X = idx % 96, Y = (idx/96) % 96, o = (idx/(96*96)) % CC, n = idx/(96*96*CC);
    float gamma = gammap[0];
    float yf = Y*0.5f - 0.25f, xf = X*0.5f - 0.25f;
    float y0f = floorf(yf), x0f = floorf(xf);
    float tyy = yf - y0f, txx = xf - x0f;
    int y0 = (int)y0f, x0 = (int)x0f;
    int iy0 = max(y0,0), iy1 = min(y0+1,GG-1);
    int ix0 = max(x0,0), ix1 = min(x0+1,GG-1);
    const float* pp = po + (size_t)(n*CC + o)*LL;
    float v00 = pp[iy0*GG+ix0], v01 = pp[iy0*GG+ix1];
    float v10 = pp[iy1*GG+ix0], v11 = pp[iy1*GG+ix1];
    float vy0 = v00 + txx*(v01-v00);
    float vy1 = v10 + txx*(v11-v10);
    float bil = vy0 + tyy*(vy1-vy0);
    out[idx] = gamma*(bil + bproj[o]) + x[idx];
}

extern "C" void kernel_launch(void* const* d_in, const int* in_sizes, int n_in,
                              void* d_out, int out_size, void* d_ws, size_t ws_size,
                              hipStream_t stream) {
    const float* x   = (const float*)d_in[0];
    const float* Wq  = (const float*)d_in[1];
    const float* Wk  = (const float*)d_in[2];
    const float* Wv  = (const float*)d_in[3];
    const float* Wgx = (const float*)d_in[4];
    const float* Wgy = (const float*)d_in[5];
    const float* ab  = (const float*)d_in[6];
    const float* Wp  = (const float*)d_in[7];
    const float* bp  = (const float*)d_in[8];
    const float* gm  = (const float*)d_in[9];
    float* ws = (float*)d_ws;
    float* xs  = ws + OFF_XS;
    _Float16* vbT = (_Float16*)(ws + OFF_VBT);
    _Float16* ebT = (_Float16*)(ws + OFF_EBT);
    float* qbp = ws + OFF_QB;
    _Float16* vtb = (_Float16*)(ws + OFF_VT);
    float* aop = ws + OFF_AO;
    float* ebp = ws + OFF_EB;
    float* ptxp= ws + OFF_PTX;
    float* ptyp= ws + OFF_PTY;
    float* wbp = ws + OFF_WB;
    float* pop = ws + OFF_PO;      // aliases qb
    float* out = (float*)d_out;

    k_extract<<<(NB*CC*LL + 255)/256, 256, 0, stream>>>(x, xs);
    k_wb<<<HEADS, 256, 0, stream>>>(Wk, ab, wbp);
    k_ptab<<<dim3(PTAB_N, 2), 256, 0, stream>>>(Wgx, Wgy, ptxp, ptyp);
    k_eb<<<dim3(LL/256, NB), 256, 0, stream>>>(xs, wbp, ebp);
    k_gemm_qv<<<dim3(LL/64, 8, NB), 256, 0, stream>>>(Wq, Wv, xs, qbp, vtb);
    k_vtr<<<dim3(NB*HEADS, 6), 256, 0, stream>>>(vtb, ebp, vbT, ebT);
    k_attn<<<dim3(LL/64, NB*HEADS), 256, 0, stream>>>(qbp, vbT, ebT, ptxp, ptyp, aop);
    k_gemm_proj<<<dim3(LL/64, 4, NB), 256, 0, stream>>>(Wp, aop, pop);
    k_final<<<(NB*CC*96*96 + 255)/256, 256, 0, stream>>>(x, pop, bp, gm, out);
}